// Round 5
// baseline (186.593 us; speedup 1.0000x reference)
//
#include <hip/hip_runtime.h>
#include <stdint.h>

#define B_ 16
#define S_ 128
#define H_ 768
#define K_ 4
#define L_ 2
#define T_ (B_*S_)   // 2048

typedef __attribute__((ext_vector_type(4))) float f32x4;
typedef __attribute__((ext_vector_type(8))) short s16x8;
typedef __bf16 bf16x8 __attribute__((ext_vector_type(8)));
typedef unsigned short u16;

// ---------- bf16 helpers ----------
__device__ inline u16 f2bf(float f) {
    union { float f; uint32_t u; } v; v.f = f;
    uint32_t u = v.u;
    return (u16)((u + 0x7fffu + ((u >> 16) & 1u)) >> 16);
}

__device__ inline ushort4 f2bf4(float4 v) {
    ushort4 r; r.x = f2bf(v.x); r.y = f2bf(v.y); r.z = f2bf(v.z); r.w = f2bf(v.w);
    return r;
}

// ---------- MFMA wrapper: tolerant to either builtin signature (short8 / bf16x8) ----------
template <typename T>
__device__ inline auto mfma_impl(T a, T b, f32x4 c, int)
    -> decltype(__builtin_amdgcn_mfma_f32_16x16x32_bf16(a, b, c, 0, 0, 0)) {
    return __builtin_amdgcn_mfma_f32_16x16x32_bf16(a, b, c, 0, 0, 0);
}
template <typename T>
__device__ inline f32x4 mfma_impl(T a, T b, f32x4 c, long) {
    return __builtin_amdgcn_mfma_f32_16x16x32_bf16(
        __builtin_bit_cast(bf16x8, a), __builtin_bit_cast(bf16x8, b), c, 0, 0, 0);
}
__device__ inline f32x4 mfma16(s16x8 a, s16x8 b, f32x4 c) {
    return mfma_impl(a, b, c, 0);
}

// ---------- async global->LDS, 16B/lane ----------
__device__ inline void gload_lds16(const void* g, void* l) {
    __builtin_amdgcn_global_load_lds(
        (__attribute__((address_space(1))) void*)(g),
        (__attribute__((address_space(3))) void*)(l), 16, 0, 0);
}

// ---- 256-thread (4-wave) stage of a 128x64-bf16 tile (gemm2; 128-B rows, XOR swz) ----
__device__ inline void stage_tile(const char* gbase, int rowStrideBytes, u16* lds, int tid) {
    const int lane = tid & 63;
    const int w = tid >> 6;
    const int lr = lane >> 3;
    const int cb = (lane & 7) << 4;
    #pragma unroll
    for (int j = 0; j < 4; ++j) {
        const int seg = j * 4 + w;
        const int row = seg * 8 + lr;
        const int sb = cb ^ ((row & 7) << 4);
        gload_lds16(gbase + (size_t)row * rowStrideBytes + sb, lds + seg * 512);
    }
}

// ---- 256-thread stage of a 64x64-bf16 tile (gemm2) ----
__device__ inline void stage64(const char* gbase, int rowStrideBytes, char* lds, int tid) {
    const int lane = tid & 63;
    const int w = tid >> 6;
    const int lr = lane >> 3;
    const int cb = (lane & 7) << 4;
    #pragma unroll
    for (int j = 0; j < 2; ++j) {
        const int seg = j * 4 + w;
        const int row = seg * 8 + lr;
        const int sb = cb ^ ((row & 7) << 4);
        gload_lds16(gbase + (size_t)row * rowStrideBytes + sb, lds + seg * 1024);
    }
}

// Swizzled ds_read_b128 (gemm2 tiles; 128-B rows)
__device__ inline s16x8 read_frag(const u16* lds, int row, int colByte) {
    const int bir = colByte ^ ((row & 7) << 4);
    return *(const s16x8*)((const char*)lds + row * 128 + bir);
}

// Swizzled fragment read for 64-B rows ([*][32] bf16): cb ^= ((row>>1)&3)<<4
__device__ inline s16x8 rf32s(const u16* lds, int row, int cb) {
    const int bir = cb ^ (((row >> 1) & 3) << 4);
    return *(const s16x8*)((const char*)lds + row * 64 + bir);
}

// ---------- prep kernels ----------
__global__ void prep_x(const float* __restrict__ sent, u16* __restrict__ X0) {
    const int i4 = blockIdx.x * blockDim.x + threadIdx.x;
    if (i4 < T_ * H_ / 4) ((ushort4*)X0)[i4] = f2bf4(((const float4*)sent)[i4]);
}

// adjA[p][b][t][s]: p=dir*4+k; dir 0 (in): adj[b,k,s,t] (transposed), dir 1 (out): adj[b,k,t,s]
__global__ void prep_adj(const float* __restrict__ adj, u16* __restrict__ adjA) {
    const int idx = blockIdx.x * blockDim.x + threadIdx.x;
    const int s = idx & 127;
    const int t = (idx >> 7) & 127;
    const int b = (idx >> 14) & 15;
    const int p = idx >> 18;
    const int dir = p >> 2, k = p & 3;
    const float v = dir ? adj[(((size_t)b * K_ + k) * S_ + t) * S_ + s]
                        : adj[(((size_t)b * K_ + k) * S_ + s) * S_ + t];
    adjA[idx] = f2bf(v);
}

// ---------- weight pack: fragment-ordered bf16 ----------
// Wpk[l][mat(17)][nT(48)][kT(24)][lane(64)][8 bf16]; mat = p*2+slot for p<8, 16 = loop.
// Chunk (nT,kT), lane l: W[nT*16 + (l&15)][kT*32 + (l>>4)*8 + 0..7]
__global__ void pack_weights(const float* __restrict__ W_in,  const float* __restrict__ W_out,
                             const float* __restrict__ Wg_in, const float* __restrict__ Wg_out,
                             const float* __restrict__ W_loop, u16* __restrict__ Wpk) {
    __shared__ float slab[16][772];   // +4 pad breaks bank aliasing
    const int tid = threadIdx.x;
    const int bid = blockIdx.x;               // l*17*48 + mat*48 + nT
    const int nT  = bid % 48;
    const int mat = (bid / 48) % 17;
    const int l   = bid / (48 * 17);

    const float* src;
    if (mat < 16) {
        const int p = mat >> 1, slot = mat & 1;
        const int dir = p >> 2, k = p & 3;
        const float* t = slot ? (dir ? Wg_out : Wg_in) : (dir ? W_out : W_in);
        src = t + ((size_t)l * K_ + k) * (H_ * H_);
    } else {
        src = W_loop + (size_t)l * (H_ * H_);
    }
    // load 16 rows x 768 cols fp32, coalesced
    #pragma unroll
    for (int it = 0; it < 12; ++it) {
        const int idx = it * 256 + tid;          // float4 index, 3072 total
        const int row = idx / 192, c4 = idx % 192;
        *(float4*)&slab[row][c4 * 4] = ((const float4*)(src + (size_t)(nT * 16 + row) * H_))[c4];
    }
    __syncthreads();
    const int q = tid >> 6, lane = tid & 63;
    const int n = lane & 15, ks = lane >> 4;
    u16* outBase = Wpk + ((((size_t)l * 17 + mat) * 48 + nT) * 24) * 512;
    #pragma unroll
    for (int it = 0; it < 6; ++it) {
        const int kT = it * 4 + q;
        u16 tmp[8];
        #pragma unroll
        for (int u = 0; u < 8; ++u) tmp[u] = f2bf(slab[n][kT * 32 + ks * 8 + u]);
        s16x8 v;
        #pragma unroll
        for (int u = 0; u < 8; ++u) v[u] = (short)tmp[u];
        *(s16x8*)(outBase + (size_t)kT * 512 + lane * 8) = v;
    }
}

// ---------- GEMM 1: B-from-registers (packed), A-only LDS dbuf, counted-vmcnt pipeline ----
// BM=128 tok, BN=128 h (rel+gate), BK=32, 24 K-tiles; 4 waves 2m x 2n, per-wave 64x64 x2.
// LDS = 2 x 8 KB (A only). One raw s_barrier + vmcnt(8) per K-tile; B regs double-buffered.
// grid 816: p<8: 768 (p,y(6),m(16)); p=8: 48 (y(3),m(16)). XCD-swizzled (816 = 8*102).
__global__ __launch_bounds__(256, 2)
void gemm1_kernel(const u16* __restrict__ Xb, const u16* __restrict__ Wpk,
                  const float* __restrict__ bg_in, const float* __restrict__ bg_out,
                  const float* __restrict__ b_in,  const float* __restrict__ b_out,
                  int layer,
                  u16* __restrict__ Rel2, float* __restrict__ SBuf) {
    __shared__ __align__(16) char smem[16384];

    const int tid = threadIdx.x;
    const int lane = tid & 63;
    const int w = tid >> 6;
    const int wm = w >> 1;                 // 0..1
    const int wn = w & 1;                  // 0..1
    const int l15 = lane & 15;
    const int hi16 = (lane >> 4) << 4;

    // decode XCD-swizzled task id
    const int id = blockIdx.x;
    const int id2 = (id & 7) * 102 + (id >> 3);   // bijective, 816 = 8*102
    int p, y, m;
    if (id2 < 768) { p = id2 / 96; const int r = id2 % 96; y = r / 16; m = r % 16; }
    else           { const int q = id2 - 768; p = 8; y = q / 16; m = q % 16; }
    const int m0 = m * 128;

    const u16* pkL = Wpk + (size_t)layer * 17 * 589824;
    const int matR = (p < 8) ? p * 2     : 16;
    const int matG = (p < 8) ? p * 2 + 1 : 16;
    const int nbr  = (p < 8) ? y * 8     : y * 16;
    const int nbg  = (p < 8) ? y * 8     : y * 16 + 8;
    const u16* pR = pkL + ((size_t)matR * 48 + nbr + wn * 4) * (24 * 512) + lane * 8;
    const u16* pG = pkL + ((size_t)matG * 48 + nbg + wn * 4) * (24 * 512) + lane * 8;
    const char* gA = (const char*)Xb + (size_t)m0 * (H_ * 2);

    auto STAGE_A = [&](int kt, int c) {
        char* base = smem + c * 8192;
        #pragma unroll
        for (int j = 0; j < 2; ++j) {
            const int rr = (j * 4 + w) * 16 + (lane >> 2);        // 0..127
            const int cbl = (lane & 3) << 4;
            const int sc = cbl ^ (((rr >> 1) & 3) << 4);          // inverse swizzle on source
            gload_lds16(gA + (size_t)rr * (H_ * 2) + kt * 64 + sc,
                        base + (j * 4 + w) * 1024);
        }
    };
    auto LOADB = [&](s16x8* dst, int kt) {
        #pragma unroll
        for (int j = 0; j < 4; ++j) {
            dst[j]     = *(const s16x8*)(pR + ((size_t)j * 24 + kt) * 512);
            dst[4 + j] = *(const s16x8*)(pG + ((size_t)j * 24 + kt) * 512);
        }
    };

    const f32x4 zf = {0.f, 0.f, 0.f, 0.f};
    f32x4 accr[4][4], accg[4][4];
    #pragma unroll
    for (int i = 0; i < 4; ++i)
        #pragma unroll
        for (int j = 0; j < 4; ++j) { accr[i][j] = zf; accg[i][j] = zf; }

    s16x8 bA[8], bB[8];

    // prologue: A(0) then B(0); order pinned so vmcnt(8) counts A as oldest
    STAGE_A(0, 0);
    __builtin_amdgcn_sched_barrier(0);
    LOADB(bA, 0);

    auto body = [&](int t, s16x8* cur, s16x8* nxt, bool pf) {
        asm volatile("s_waitcnt vmcnt(8)" ::: "memory");   // A(t) staged; B(t) may still fly
        __builtin_amdgcn_s_barrier();
        const u16* lA = (const u16*)(smem + (t & 1) * 8192);
        s16x8 a[4];
        #pragma unroll
        for (int i = 0; i < 4; ++i)
            a[i] = rf32s(lA, wm * 64 + i * 16 + l15, hi16);
        if (pf) {
            STAGE_A(t + 1, (t + 1) & 1);
            __builtin_amdgcn_sched_barrier(0);
            LOADB(nxt, t + 1);
        }
        __builtin_amdgcn_s_setprio(1);
        #pragma unroll
        for (int i = 0; i < 4; ++i) {
            #pragma unroll
            for (int j = 0; j < 4; ++j) {
                accr[i][j] = mfma16(a[i], cur[j],     accr[i][j]);
                accg[i][j] = mfma16(a[i], cur[4 + j], accg[i][j]);
            }
        }
        __builtin_amdgcn_s_setprio(0);
    };

    for (int t = 0; t < 24; t += 2) {
        body(t,     bA, bB, true);
        body(t + 1, bB, bA, t + 1 < 23);
    }

    // ---------------- epilogue (wave-local) ----------------
    if (p < 8) {
        const int dir = p >> 2, k = p & 3;
        const float* bgp = (dir ? bg_out : bg_in) + ((size_t)layer * K_ + k) * H_;
        const float* brp = (dir ? b_out  : b_in ) + ((size_t)layer * K_ + k) * H_;
        #pragma unroll
        for (int j = 0; j < 4; ++j) {
            const int h = y * 128 + wn * 64 + j * 16 + l15;
            const float bgv = bgp[h];
            const float brv = brp[h];
            #pragma unroll
            for (int i = 0; i < 4; ++i) {
                const int s0 = wm * 64 + i * 16 + ((lane >> 4) << 2);   // 0..127
                u16 tmp[4];
                #pragma unroll
                for (int r = 0; r < 4; ++r) {
                    const float g = accg[i][j][r] + bgv;
                    const float v = accr[i][j][r] + brv;
                    tmp[r] = f2bf(0.5f * v / (1.f + __expf(-g)));
                }
                ushort4 pk; pk.x = tmp[0]; pk.y = tmp[1]; pk.z = tmp[2]; pk.w = tmp[3];
                *(ushort4*)(Rel2 + (((size_t)p * B_ + m) * H_ + h) * S_ + s0) = pk;
            }
        }
    } else {
        #pragma unroll
        for (int j = 0; j < 4; ++j) {
            const int h1 = y * 256 + wn * 64 + j * 16 + l15;
            const int h2 = h1 + 128;
            #pragma unroll
            for (int i = 0; i < 4; ++i) {
                const int tg = m0 + wm * 64 + i * 16 + ((lane >> 4) << 2);
                #pragma unroll
                for (int r = 0; r < 4; ++r) {
                    SBuf[(size_t)(tg + r) * H_ + h1] = accr[i][j][r];
                    SBuf[(size_t)(tg + r) * H_ + h2] = accg[i][j][r];
                }
            }
        }
    }
}

// ---------- GEMM 2: adjacency contraction + loop term + ReLU ----------
// 2-phase dbuf; grid (12 h-tiles of 64, 16 batches), block 256 (4 waves 2x2).
__global__ __launch_bounds__(256, 2)
void gemm2_kernel(const u16* __restrict__ adjA, const u16* __restrict__ Rel2,
                  const float* __restrict__ SBuf,
                  u16* __restrict__ Xn, float* __restrict__ Out, int lastLayer) {
    __shared__ __align__(16) char smem2[49152];   // 2 x (A 16K + B 8K)

    const int tid = threadIdx.x;
    const int lane = tid & 63;
    const int w = tid >> 6;
    const int wm = w >> 1, wn = w & 1;
    const int l15 = lane & 15;
    const int hi16 = (lane >> 4) << 4;
    const int h0 = blockIdx.x * 64;
    const int b = blockIdx.y;

    auto STAGE = [&](int q, int c) {
        const int p = q >> 1, sc = q & 1;
        const char* Ab = (const char*)adjA + ((size_t)p * B_ + b) * (S_ * S_ * 2) + sc * 128;
        const char* Bb = (const char*)Rel2 + (((size_t)p * B_ + b) * H_ + h0) * (S_ * 2) + sc * 128;
        char* base = smem2 + c * 24576;
        stage_tile(Ab, S_ * 2, (u16*)base, tid);
        stage64(Bb, S_ * 2, base + 16384, tid);
    };

    const f32x4 zf = {0.f, 0.f, 0.f, 0.f};
    f32x4 acc[4][2];
    #pragma unroll
    for (int i = 0; i < 4; ++i)
        #pragma unroll
        for (int j = 0; j < 2; ++j) acc[i][j] = zf;

    STAGE(0, 0);
    __syncthreads();

    for (int q = 0; q < 16; ++q) {
        const int c = q & 1;
        if (q < 15) STAGE(q + 1, c ^ 1);
        const u16* lA = (const u16*)(smem2 + c * 24576);
        const u16* lB = (const u16*)(smem2 + c * 24576 + 16384);
        #pragma unroll
        for (int kq = 0; kq < 2; ++kq) {
            const int ck = kq * 64 + hi16;
            s16x8 a[4], bb[2];
            #pragma unroll
            for (int i = 0; i < 4; ++i)
                a[i] = read_frag(lA, wm * 64 + i * 16 + l15, ck);
            #pragma unroll
            for (int j = 0; j < 2; ++j)
                bb[j] = read_frag(lB, wn * 32 + j * 16 + l15, ck);
            #pragma unroll
            for (int i = 0; i < 4; ++i)
                #pragma unroll
                for (int j = 0; j < 2; ++j)
                    acc[i][j] = mfma16(a[i], bb[j], acc[i][j]);
        }
        __syncthreads();
    }

    #pragma unroll
    for (int i = 0; i < 4; ++i) {
        const int tl = wm * 64 + i * 16 + ((lane >> 4) << 2);
        #pragma unroll
        for (int j = 0; j < 2; ++j) {
            const int h = h0 + wn * 32 + j * 16 + l15;
            #pragma unroll
            for (int r = 0; r < 4; ++r) {
                const size_t t = (size_t)b * S_ + tl + r;
                float v = acc[i][j][r] + SBuf[t * H_ + h];
                v = fmaxf(v, 0.f);
                if (lastLayer) Out[t * H_ + h] = v;
                else           Xn[t * H_ + h] = f2bf(v);
            }
        }
    }
}

// ---------- launch ----------
extern "C" void kernel_launch(void* const* d_in, const int* in_sizes, int n_in,
                              void* d_out, int out_size, void* d_ws, size_t ws_size,
                              hipStream_t stream) {
    const float* sent   = (const float*)d_in[0];
    const float* adj    = (const float*)d_in[1];
    const float* W_in   = (const float*)d_in[2];
    const float* b_in   = (const float*)d_in[3];
    const float* W_out  = (const float*)d_in[4];
    const float* b_out  = (const float*)d_in[5];
    const float* Wg_in  = (const float*)d_in[6];
    const float* bg_in  = (const float*)d_in[7];
    const float* Wg_out = (const float*)d_in[8];
    const float* bg_out = (const float*)d_in[9];
    const float* W_loop = (const float*)d_in[10];

    char* ws = (char*)d_ws;
    u16* Wpk    = (u16*)(ws);                  // L*17*48*24*1024 = 40,108,032 B
    u16* adjA   = (u16*)(ws + 40108032);       //  4,194,304 B
    u16* X0     = (u16*)(ws + 44302336);       //  3,145,728 B
    u16* X1     = (u16*)(ws + 47448064);       //  3,145,728 B
    u16* Rel2   = (u16*)(ws + 50593792);       // 25,165,824 B
    float* SBuf = (float*)(ws + 75759616);     //  6,291,456 B  (end 82,051,072)

    prep_x<<<1536, 256, 0, stream>>>(sent, X0);
    prep_adj<<<8192, 256, 0, stream>>>(adj, adjA);
    pack_weights<<<L_ * 17 * 48, 256, 0, stream>>>(W_in, W_out, Wg_in, Wg_out, W_loop, Wpk);

    u16* Xc = X0;
    u16* Xn = X1;
    for (int l = 0; l < L_; ++l) {
        gemm1_kernel<<<816, 256, 0, stream>>>(Xc, Wpk, bg_in, bg_out, b_in, b_out,
                                              l, Rel2, SBuf);
        gemm2_kernel<<<dim3(12, 16), 256, 0, stream>>>(adjA, Rel2, SBuf, Xn,
                                                       (float*)d_out, l == L_ - 1);
        u16* t = Xc; Xc = Xn; Xn = t;
    }
}

// Round 6
// 174.706 us; speedup vs baseline: 1.0680x; 1.0680x over previous
//
#include <hip/hip_runtime.h>
#include <stdint.h>

#define B_ 16
#define S_ 128
#define H_ 768
#define K_ 4
#define L_ 2
#define T_ (B_*S_)   // 2048

typedef __attribute__((ext_vector_type(4))) float f32x4;
typedef __attribute__((ext_vector_type(8))) short s16x8;
typedef __bf16 bf16x8 __attribute__((ext_vector_type(8)));
typedef unsigned short u16;

// ---------- bf16 helpers ----------
__device__ inline u16 f2bf(float f) {
    union { float f; uint32_t u; } v; v.f = f;
    uint32_t u = v.u;
    return (u16)((u + 0x7fffu + ((u >> 16) & 1u)) >> 16);
}

__device__ inline ushort4 f2bf4(float4 v) {
    ushort4 r; r.x = f2bf(v.x); r.y = f2bf(v.y); r.z = f2bf(v.z); r.w = f2bf(v.w);
    return r;
}

// ---------- MFMA wrapper: tolerant to either builtin signature (short8 / bf16x8) ----------
template <typename T>
__device__ inline auto mfma_impl(T a, T b, f32x4 c, int)
    -> decltype(__builtin_amdgcn_mfma_f32_16x16x32_bf16(a, b, c, 0, 0, 0)) {
    return __builtin_amdgcn_mfma_f32_16x16x32_bf16(a, b, c, 0, 0, 0);
}
template <typename T>
__device__ inline f32x4 mfma_impl(T a, T b, f32x4 c, long) {
    return __builtin_amdgcn_mfma_f32_16x16x32_bf16(
        __builtin_bit_cast(bf16x8, a), __builtin_bit_cast(bf16x8, b), c, 0, 0, 0);
}
__device__ inline f32x4 mfma16(s16x8 a, s16x8 b, f32x4 c) {
    return mfma_impl(a, b, c, 0);
}

// ---------- async global->LDS, 16B/lane ----------
__device__ inline void gload_lds16(const void* g, void* l) {
    __builtin_amdgcn_global_load_lds(
        (__attribute__((address_space(1))) void*)(g),
        (__attribute__((address_space(3))) void*)(l), 16, 0, 0);
}

// ---- 256-thread (4-wave) stage of a 128x64-bf16 tile (gemm2; 128-B rows, XOR swz) ----
__device__ inline void stage_tile(const char* gbase, int rowStrideBytes, u16* lds, int tid) {
    const int lane = tid & 63;
    const int w = tid >> 6;
    const int lr = lane >> 3;
    const int cb = (lane & 7) << 4;
    #pragma unroll
    for (int j = 0; j < 4; ++j) {
        const int seg = j * 4 + w;
        const int row = seg * 8 + lr;
        const int sb = cb ^ ((row & 7) << 4);
        gload_lds16(gbase + (size_t)row * rowStrideBytes + sb, lds + seg * 512);
    }
}

// ---- 256-thread stage of a 64x64-bf16 tile (gemm2) ----
__device__ inline void stage64(const char* gbase, int rowStrideBytes, char* lds, int tid) {
    const int lane = tid & 63;
    const int w = tid >> 6;
    const int lr = lane >> 3;
    const int cb = (lane & 7) << 4;
    #pragma unroll
    for (int j = 0; j < 2; ++j) {
        const int seg = j * 4 + w;
        const int row = seg * 8 + lr;
        const int sb = cb ^ ((row & 7) << 4);
        gload_lds16(gbase + (size_t)row * rowStrideBytes + sb, lds + seg * 1024);
    }
}

// Swizzled ds_read_b128 (gemm2 tiles; 128-B rows)
__device__ inline s16x8 read_frag(const u16* lds, int row, int colByte) {
    const int bir = colByte ^ ((row & 7) << 4);
    return *(const s16x8*)((const char*)lds + row * 128 + bir);
}

// Swizzled fragment read for A super-tile (256-B rows, [128 tok][128 K] bf16)
__device__ inline s16x8 rfA(const u16* lds, int row, int cb) {
    const int bir = cb ^ ((row & 7) << 4);
    return *(const s16x8*)((const char*)lds + row * 256 + bir);
}

// ---------- prep kernels ----------
__global__ void prep_x(const float* __restrict__ sent, u16* __restrict__ X0) {
    const int i4 = blockIdx.x * blockDim.x + threadIdx.x;
    if (i4 < T_ * H_ / 4) ((ushort4*)X0)[i4] = f2bf4(((const float4*)sent)[i4]);
}

// adjA[p][b][t][s]: p=dir*4+k; dir 0 (in): adj[b,k,s,t] (transposed), dir 1 (out): adj[b,k,t,s]
__global__ void prep_adj(const float* __restrict__ adj, u16* __restrict__ adjA) {
    const int idx = blockIdx.x * blockDim.x + threadIdx.x;
    const int s = idx & 127;
    const int t = (idx >> 7) & 127;
    const int b = (idx >> 14) & 15;
    const int p = idx >> 18;
    const int dir = p >> 2, k = p & 3;
    const float v = dir ? adj[(((size_t)b * K_ + k) * S_ + t) * S_ + s]
                        : adj[(((size_t)b * K_ + k) * S_ + s) * S_ + t];
    adjA[idx] = f2bf(v);
}

// ---------- weight pack: fragment-ordered bf16 ----------
// Wpk[l][mat(17)][nT(48)][kT(24)][lane(64)][8 bf16]; mat = p*2+slot for p<8, 16 = loop.
// Chunk (nT,kT), lane l: W[nT*16 + (l&15)][kT*32 + (l>>4)*8 + 0..7]
__global__ void pack_weights(const float* __restrict__ W_in,  const float* __restrict__ W_out,
                             const float* __restrict__ Wg_in, const float* __restrict__ Wg_out,
                             const float* __restrict__ W_loop, u16* __restrict__ Wpk) {
    __shared__ float slab[16][772];   // +4 pad breaks bank aliasing
    const int tid = threadIdx.x;
    const int bid = blockIdx.x;               // l*17*48 + mat*48 + nT
    const int nT  = bid % 48;
    const int mat = (bid / 48) % 17;
    const int l   = bid / (48 * 17);

    const float* src;
    if (mat < 16) {
        const int p = mat >> 1, slot = mat & 1;
        const int dir = p >> 2, k = p & 3;
        const float* t = slot ? (dir ? Wg_out : Wg_in) : (dir ? W_out : W_in);
        src = t + ((size_t)l * K_ + k) * (H_ * H_);
    } else {
        src = W_loop + (size_t)l * (H_ * H_);
    }
    #pragma unroll
    for (int it = 0; it < 12; ++it) {
        const int idx = it * 256 + tid;          // float4 index, 3072 total
        const int row = idx / 192, c4 = idx % 192;
        *(float4*)&slab[row][c4 * 4] = ((const float4*)(src + (size_t)(nT * 16 + row) * H_))[c4];
    }
    __syncthreads();
    const int q = tid >> 6, lane = tid & 63;
    const int n = lane & 15, ks = lane >> 4;
    u16* outBase = Wpk + ((((size_t)l * 17 + mat) * 48 + nT) * 24) * 512;
    #pragma unroll
    for (int it = 0; it < 6; ++it) {
        const int kT = it * 4 + q;
        u16 tmp[8];
        #pragma unroll
        for (int u = 0; u < 8; ++u) tmp[u] = f2bf(slab[n][kT * 32 + ks * 8 + u]);
        s16x8 v;
        #pragma unroll
        for (int u = 0; u < 8; ++u) v[u] = (short)tmp[u];
        *(s16x8*)(outBase + (size_t)kT * 512 + lane * 8) = v;
    }
}

// ---------- GEMM 1: reg-B + A super-tile, barrier-free subtiles ----------
// BM=128 tok, BN=128 h (rel+gate), BK=32, 24 K-subtiles grouped into 6 super-tiles of 4.
// A super-tile [128][128] bf16 = 32 KB, double-buffered (64 KB LDS) -> 2 blocks/CU.
// One vmcnt(8)+s_barrier per super-tile; B streamed global->reg, distance-1 dbuf.
// grid 816 flat: p<8: (p,y(6),m(16)); p=8: (y(3),m(16)). XCD-swizzled (816 = 8*102).
__global__ __launch_bounds__(256, 2)
void gemm1_kernel(const u16* __restrict__ Xb, const u16* __restrict__ Wpk,
                  const float* __restrict__ bg_in, const float* __restrict__ bg_out,
                  const float* __restrict__ b_in,  const float* __restrict__ b_out,
                  int layer,
                  u16* __restrict__ Rel2, float* __restrict__ SBuf) {
    __shared__ __align__(16) char smem[65536];

    const int tid = threadIdx.x;
    const int lane = tid & 63;
    const int w = tid >> 6;
    const int wm = w >> 1;                 // 0..1
    const int wn = w & 1;                  // 0..1
    const int l15 = lane & 15;
    const int ks = lane >> 4;
    const int hi16 = ks << 4;

    // decode XCD-swizzled task id
    const int id = blockIdx.x;
    const int id2 = (id & 7) * 102 + (id >> 3);   // bijective, 816 = 8*102
    int p, y, m;
    if (id2 < 768) { p = id2 / 96; const int r = id2 % 96; y = r / 16; m = r % 16; }
    else           { const int q = id2 - 768; p = 8; y = q / 16; m = q % 16; }
    const int m0 = m * 128;

    const u16* pkL = Wpk + (size_t)layer * 17 * 589824;
    const int matR = (p < 8) ? p * 2     : 16;
    const int matG = (p < 8) ? p * 2 + 1 : 16;
    const int nbr  = (p < 8) ? y * 8     : y * 16;
    const int nbg  = (p < 8) ? y * 8     : y * 16 + 8;
    const u16* pR = pkL + ((size_t)matR * 48 + nbr + wn * 4) * (24 * 512) + lane * 8;
    const u16* pG = pkL + ((size_t)matG * 48 + nbg + wn * 4) * (24 * 512) + lane * 8;
    const char* gA = (const char*)Xb + (size_t)m0 * (H_ * 2);

    // stage A super-tile S ([128 tok][128 K] -> 256-B rows, c16 ^= row&7 swizzle,
    // applied on the SOURCE so LDS dest stays wave-linear)
    auto STAGE_A = [&](int S, int c) {
        char* base = smem + c * 32768;
        #pragma unroll
        for (int j = 0; j < 8; ++j) {
            const int row = j * 16 + w * 4 + ks;          // 0..127
            const int sc = (l15 << 4) ^ ((row & 7) << 4); // source byte col within 256
            gload_lds16(gA + (size_t)row * (H_ * 2) + S * 256 + sc,
                        base + j * 4096 + w * 1024);
        }
    };
    auto LOADB = [&](s16x8* dst, int kt) {
        #pragma unroll
        for (int j = 0; j < 4; ++j) {
            dst[j]     = *(const s16x8*)(pR + ((size_t)j * 24 + kt) * 512);
            dst[4 + j] = *(const s16x8*)(pG + ((size_t)j * 24 + kt) * 512);
        }
    };

    const f32x4 zf = {0.f, 0.f, 0.f, 0.f};
    f32x4 accr[4][4], accg[4][4];
    #pragma unroll
    for (int i = 0; i < 4; ++i)
        #pragma unroll
        for (int j = 0; j < 4; ++j) { accr[i][j] = zf; accg[i][j] = zf; }

    s16x8 bA[8], bB[8];

    #define DO_SUB(LA, KTL, BUF)                                               \
        {                                                                      \
            s16x8 a[4];                                                        \
            _Pragma("unroll") for (int i = 0; i < 4; ++i)                      \
                a[i] = rfA(LA, wm * 64 + i * 16 + l15, (KTL) * 64 + hi16);     \
            __builtin_amdgcn_s_setprio(1);                                     \
            _Pragma("unroll") for (int i = 0; i < 4; ++i) {                    \
                _Pragma("unroll") for (int j = 0; j < 4; ++j) {                \
                    accr[i][j] = mfma16(a[i], BUF[j],     accr[i][j]);         \
                    accg[i][j] = mfma16(a[i], BUF[4 + j], accg[i][j]);         \
                }                                                              \
            }                                                                  \
            __builtin_amdgcn_s_setprio(0);                                     \
        }

    // prologue
    STAGE_A(0, 0);
    LOADB(bA, 0);
    asm volatile("s_waitcnt vmcnt(0)" ::: "memory");
    __builtin_amdgcn_s_barrier();
    __builtin_amdgcn_sched_barrier(0);

    for (int S = 0; S < 6; ++S) {
        const u16* lA = (const u16*)(smem + (S & 1) * 32768);
        const int k0 = S * 4;
        // subtile 0: B(k0+1) first (stays oldest), then A-stage for S+1
        LOADB(bB, k0 + 1);
        if (S < 5) STAGE_A(S + 1, (S & 1) ^ 1);
        DO_SUB(lA, 0, bA)
        // subtile 1
        LOADB(bA, k0 + 2);
        DO_SUB(lA, 1, bB)
        // subtile 2
        LOADB(bB, k0 + 3);
        DO_SUB(lA, 2, bA)
        // subtile 3
        if (S < 5) LOADB(bA, k0 + 4);
        DO_SUB(lA, 3, bB)
        // super-tile boundary: drain A-stage (and older), keep newest B batch flying
        asm volatile("s_waitcnt vmcnt(8)" ::: "memory");
        __builtin_amdgcn_s_barrier();
        __builtin_amdgcn_sched_barrier(0);
    }
    #undef DO_SUB

    // ---------------- epilogue (wave-local) ----------------
    if (p < 8) {
        const int dir = p >> 2, k = p & 3;
        const float* bgp = (dir ? bg_out : bg_in) + ((size_t)layer * K_ + k) * H_;
        const float* brp = (dir ? b_out  : b_in ) + ((size_t)layer * K_ + k) * H_;
        #pragma unroll
        for (int j = 0; j < 4; ++j) {
            const int h = y * 128 + wn * 64 + j * 16 + l15;
            const float bgv = bgp[h];
            const float brv = brp[h];
            #pragma unroll
            for (int i = 0; i < 4; ++i) {
                const int s0 = wm * 64 + i * 16 + ks * 4;   // 0..127
                u16 tmp[4];
                #pragma unroll
                for (int r = 0; r < 4; ++r) {
                    const float g = accg[i][j][r] + bgv;
                    const float v = accr[i][j][r] + brv;
                    tmp[r] = f2bf(0.5f * v / (1.f + __expf(-g)));
                }
                ushort4 pk; pk.x = tmp[0]; pk.y = tmp[1]; pk.z = tmp[2]; pk.w = tmp[3];
                *(ushort4*)(Rel2 + (((size_t)p * B_ + m) * H_ + h) * S_ + s0) = pk;
            }
        }
    } else {
        #pragma unroll
        for (int j = 0; j < 4; ++j) {
            const int h1 = y * 256 + wn * 64 + j * 16 + l15;
            const int h2 = h1 + 128;
            #pragma unroll
            for (int i = 0; i < 4; ++i) {
                const int tg = m0 + wm * 64 + i * 16 + ks * 4;
                #pragma unroll
                for (int r = 0; r < 4; ++r) {
                    SBuf[(size_t)(tg + r) * H_ + h1] = accr[i][j][r];
                    SBuf[(size_t)(tg + r) * H_ + h2] = accg[i][j][r];
                }
            }
        }
    }
}

// ---------- GEMM 2: adjacency contraction + loop term + ReLU ----------
// 2-phase dbuf; grid (12 h-tiles of 64, 16 batches), block 256 (4 waves 2x2).
__global__ __launch_bounds__(256, 2)
void gemm2_kernel(const u16* __restrict__ adjA, const u16* __restrict__ Rel2,
                  const float* __restrict__ SBuf,
                  u16* __restrict__ Xn, float* __restrict__ Out, int lastLayer) {
    __shared__ __align__(16) char smem2[49152];   // 2 x (A 16K + B 8K)

    const int tid = threadIdx.x;
    const int lane = tid & 63;
    const int w = tid >> 6;
    const int wm = w >> 1, wn = w & 1;
    const int l15 = lane & 15;
    const int hi16 = (lane >> 4) << 4;
    const int h0 = blockIdx.x * 64;
    const int b = blockIdx.y;

    auto STAGE = [&](int q, int c) {
        const int p = q >> 1, sc = q & 1;
        const char* Ab = (const char*)adjA + ((size_t)p * B_ + b) * (S_ * S_ * 2) + sc * 128;
        const char* Bb = (const char*)Rel2 + (((size_t)p * B_ + b) * H_ + h0) * (S_ * 2) + sc * 128;
        char* base = smem2 + c * 24576;
        stage_tile(Ab, S_ * 2, (u16*)base, tid);
        stage64(Bb, S_ * 2, base + 16384, tid);
    };

    const f32x4 zf = {0.f, 0.f, 0.f, 0.f};
    f32x4 acc[4][2];
    #pragma unroll
    for (int i = 0; i < 4; ++i)
        #pragma unroll
        for (int j = 0; j < 2; ++j) acc[i][j] = zf;

    STAGE(0, 0);
    __syncthreads();

    for (int q = 0; q < 16; ++q) {
        const int c = q & 1;
        if (q < 15) STAGE(q + 1, c ^ 1);
        const u16* lA = (const u16*)(smem2 + c * 24576);
        const u16* lB = (const u16*)(smem2 + c * 24576 + 16384);
        #pragma unroll
        for (int kq = 0; kq < 2; ++kq) {
            const int ck = kq * 64 + hi16;
            s16x8 a[4], bb[2];
            #pragma unroll
            for (int i = 0; i < 4; ++i)
                a[i] = read_frag(lA, wm * 64 + i * 16 + l15, ck);
            #pragma unroll
            for (int j = 0; j < 2; ++j)
                bb[j] = read_frag(lB, wn * 32 + j * 16 + l15, ck);
            #pragma unroll
            for (int i = 0; i < 4; ++i)
                #pragma unroll
                for (int j = 0; j < 2; ++j)
                    acc[i][j] = mfma16(a[i], bb[j], acc[i][j]);
        }
        __syncthreads();
    }

    #pragma unroll
    for (int i = 0; i < 4; ++i) {
        const int tl = wm * 64 + i * 16 + ((lane >> 4) << 2);
        #pragma unroll
        for (int j = 0; j < 2; ++j) {
            const int h = h0 + wn * 32 + j * 16 + l15;
            #pragma unroll
            for (int r = 0; r < 4; ++r) {
                const size_t t = (size_t)b * S_ + tl + r;
                float v = acc[i][j][r] + SBuf[t * H_ + h];
                v = fmaxf(v, 0.f);
                if (lastLayer) Out[t * H_ + h] = v;
                else           Xn[t * H_ + h] = f2bf(v);
            }
        }
    }
}

// ---------- launch ----------
extern "C" void kernel_launch(void* const* d_in, const int* in_sizes, int n_in,
                              void* d_out, int out_size, void* d_ws, size_t ws_size,
                              hipStream_t stream) {
    const float* sent   = (const float*)d_in[0];
    const float* adj    = (const float*)d_in[1];
    const float* W_in   = (const float*)d_in[2];
    const float* b_in   = (const float*)d_in[3];
    const float* W_out  = (const float*)d_in[4];
    const float* b_out  = (const float*)d_in[5];
    const float* Wg_in  = (const float*)d_in[6];
    const float* bg_in  = (const float*)d_in[7];
    const float* Wg_out = (const float*)d_in[8];
    const float* bg_out = (const float*)d_in[9];
    const float* W_loop = (const float*)d_in[10];

    char* ws = (char*)d_ws;
    u16* Wpk    = (u16*)(ws);                  // L*17*48*24*1024 = 40,108,032 B
    u16* adjA   = (u16*)(ws + 40108032);       //  4,194,304 B
    u16* X0     = (u16*)(ws + 44302336);       //  3,145,728 B
    u16* X1     = (u16*)(ws + 47448064);       //  3,145,728 B
    u16* Rel2   = (u16*)(ws + 50593792);       // 25,165,824 B
    float* SBuf = (float*)(ws + 75759616);     //  6,291,456 B  (end 82,051,072)

    prep_x<<<1536, 256, 0, stream>>>(sent, X0);
    prep_adj<<<8192, 256, 0, stream>>>(adj, adjA);
    pack_weights<<<L_ * 17 * 48, 256, 0, stream>>>(W_in, W_out, Wg_in, Wg_out, W_loop, Wpk);

    u16* Xc = X0;
    u16* Xn = X1;
    for (int l = 0; l < L_; ++l) {
        gemm1_kernel<<<816, 256, 0, stream>>>(Xc, Wpk, bg_in, bg_out, b_in, b_out,
                                              l, Rel2, SBuf);
        gemm2_kernel<<<dim3(12, 16), 256, 0, stream>>>(adjA, Rel2, SBuf, Xn,
                                                       (float*)d_out, l == L_ - 1);
        u16* t = Xc; Xc = Xn; Xn = t;
    }
}